// Round 11
// baseline (515.840 us; speedup 1.0000x reference)
//
#include <hip/hip_runtime.h>
#include <hip/hip_bf16.h>
#include <stdint.h>

#define DEV static __device__ __forceinline__

typedef __attribute__((ext_vector_type(4))) float f32x4;
typedef __attribute__((ext_vector_type(8))) short s16x8;
typedef __attribute__((ext_vector_type(4))) short s16x4;

constexpr int N_TOK = 32768;   // 32^3
constexpr int C_DIM = 1024;
constexpr int C3    = 3072;
constexpr int GK    = 1024;    // K for both GEMMs

DEV float bf2f(short u) { union { float f; uint32_t i; } x; x.i = ((uint32_t)(uint16_t)u) << 16; return x.f; }
DEV short f2bf(float f) { union { float f; uint32_t i; } x; x.f = f; uint32_t r = x.i + 0x7FFFu + ((x.i >> 16) & 1u); return (short)(r >> 16); }

DEV f32x4 mfma16(s16x8 a, s16x8 b, f32x4 c) {
  return __builtin_amdgcn_mfma_f32_16x16x32_bf16(a, b, c, 0, 0, 0);
}

DEV void gload16(const void* g, void* lds) {
  __builtin_amdgcn_global_load_lds((const __attribute__((address_space(1))) void*)g,
                                   (__attribute__((address_space(3))) void*)lds, 16, 0, 0);
}

#define SB() __builtin_amdgcn_sched_barrier(0)
#define WAIT_VM(N) do { asm volatile("s_waitcnt vmcnt(" #N ")" ::: "memory"); SB(); } while (0)
DEV void bar_top() { SB(); __builtin_amdgcn_s_barrier(); asm volatile("s_waitcnt lgkmcnt(0)" ::: "memory"); SB(); }
DEV void bar_end() { SB(); __builtin_amdgcn_s_barrier(); SB(); }

// ---------------- fp32 -> bf16 convert (x) + RoPE table (block 0) ----------------
__global__ void k_cvt_x(const float* __restrict__ in, short* __restrict__ outb,
                        float2* __restrict__ ctab) {
  if (blockIdx.x == 0) {
    for (int t = threadIdx.x; t < 320; t += 256) {
      int c = t / 10, fi = t % 10;
      float freq = powf(10000.0f, -(float)fi / 10.0f);
      float ph = (float)c * freq;
      ctab[t] = make_float2(cosf(ph), sinf(ph));
    }
  }
  size_t i = ((size_t)blockIdx.x * 256 + threadIdx.x) * 8;
  float4 a = *(const float4*)(in + i);
  float4 b = *(const float4*)(in + i + 4);
  s16x8 o;
  o[0] = f2bf(a.x); o[1] = f2bf(a.y); o[2] = f2bf(a.z); o[3] = f2bf(a.w);
  o[4] = f2bf(b.x); o[5] = f2bf(b.y); o[6] = f2bf(b.z); o[7] = f2bf(b.w);
  *(s16x8*)(outb + i) = o;
}

// ---------------- transpose + convert both weights (-> [ncol][K] bf16) ----------------
__global__ void k_transpose_all(const float* __restrict__ wqkv, short* __restrict__ wqkvT,
                                const float* __restrict__ wout, short* __restrict__ woutT) {
  __shared__ float t[32][33];
  int b = blockIdx.x;
  const float* in; short* outb; int rin, cin, bx, by;
  if (b < 96 * 32) {
    in = wqkv; outb = wqkvT; rin = C_DIM; cin = C3; bx = b % 96; by = b / 96;
  } else {
    b -= 96 * 32;
    in = wout; outb = woutT; rin = C_DIM; cin = C_DIM; bx = b % 32; by = b / 32;
  }
  int tx = threadIdx.x & 31, ty = threadIdx.x >> 5;
  int c0 = bx * 32, r0 = by * 32;
#pragma unroll
  for (int k = 0; k < 32; k += 8) t[ty + k][tx] = in[(size_t)(r0 + ty + k) * cin + c0 + tx];
  __syncthreads();
#pragma unroll
  for (int k = 0; k < 32; k += 8) outb[(size_t)(c0 + ty + k) * rin + r0 + tx] = f2bf(t[tx][ty + k]);
}

// ================= 256x256 8-phase GEMM (T2+T3+T4+T5) =================
#define READ_A(b, mh) do { _Pragma("unroll") for (int mi_ = 0; mi_ < 4; ++mi_) \
  _Pragma("unroll") for (int kh_ = 0; kh_ < 2; ++kh_) af[mi_ * 2 + kh_] = LDA(b, (mh) * 4 + mi_, kh_); } while (0)
#define READ_B(b, nh, bfx) do { _Pragma("unroll") for (int ni_ = 0; ni_ < 2; ++ni_) \
  _Pragma("unroll") for (int kh_ = 0; kh_ < 2; ++kh_) (bfx)[ni_ * 2 + kh_] = LDB(b, (nh) * 2 + ni_, kh_); } while (0)
#define MFMAQ(mh, nh, bfx) do { __builtin_amdgcn_s_setprio(1); \
  _Pragma("unroll") for (int mi_ = 0; mi_ < 4; ++mi_) \
  _Pragma("unroll") for (int kh_ = 0; kh_ < 2; ++kh_) \
  _Pragma("unroll") for (int ni_ = 0; ni_ < 2; ++ni_) \
    acc[(mh) * 4 + mi_][(nh) * 2 + ni_] = mfma16(af[mi_ * 2 + kh_], (bfx)[ni_ * 2 + kh_], acc[(mh) * 4 + mi_][(nh) * 2 + ni_]); \
  __builtin_amdgcn_s_setprio(0); } while (0)

DEV void gemm256_core(const short* __restrict__ A, const short* __restrict__ Bt,
                      int tileM, int tileN, short* lds, f32x4 (&acc)[8][4]) {
  const int tid = threadIdx.x;
  const int lane = tid & 63, wid = tid >> 6;
  const int wr = wid >> 2, wc = wid & 3;
  const int g = lane >> 4, r = lane & 15;

#pragma unroll
  for (int mi = 0; mi < 8; ++mi)
#pragma unroll
    for (int ni = 0; ni < 4; ++ni) acc[mi][ni] = (f32x4)0.0f;

  const short* Ag = A + (size_t)tileM * GK;
  const short* Bg = Bt + (size_t)tileN * GK;
  const int ldsA = wr * 8192;
  const int ldsB = 16384 + (wc >> 1) * 8192;
  const int brow = (wc & 1) * 64;

  auto stageA = [&](int b, int h, int kt) {
    const short* gb = Ag + (size_t)(h * 128) * GK + kt * 64;
    short* db = lds + b * 32768 + h * 8192 + (tid & 448) * 8;
#pragma unroll
    for (int i = 0; i < 2; ++i) {
      int s = i * 512 + tid;
      int row = s >> 3;
      int c = (s & 7) ^ (row & 7);
      gload16(gb + (size_t)row * GK + c * 8, db + i * 4096);
    }
  };
  auto stageB = [&](int b, int h, int kt) {
    const short* gb = Bg + (size_t)(h * 128) * GK + kt * 64;
    short* db = lds + b * 32768 + 16384 + h * 8192 + (tid & 448) * 8;
#pragma unroll
    for (int i = 0; i < 2; ++i) {
      int s = i * 512 + tid;
      int row = s >> 3;
      int c = (s & 7) ^ (row & 7);
      gload16(gb + (size_t)row * GK + c * 8, db + i * 4096);
    }
  };
  auto LDA = [&](int b, int mi, int kh) -> s16x8 {
    int row = mi * 16 + r;
    int c = (kh * 4 + g) ^ (r & 7);
    return *(const s16x8*)(lds + b * 32768 + ldsA + row * 64 + c * 8);
  };
  auto LDB = [&](int b, int ni, int kh) -> s16x8 {
    int row = brow + ni * 16 + r;
    int c = (kh * 4 + g) ^ (r & 7);
    return *(const s16x8*)(lds + b * 32768 + ldsB + row * 64 + c * 8);
  };

  s16x8 af[8], bf0[4], bf1[4];

  stageA(0, 0, 0); stageA(0, 1, 0); stageB(0, 0, 0); stageB(0, 1, 0);
  stageB(1, 0, 1); stageB(1, 1, 1);
  WAIT_VM(4);
  __builtin_amdgcn_s_barrier();

#pragma unroll 1
  for (int t = 0; t < 16; t += 2) {
    const bool s2 = (t + 2 < 16), s3 = (t + 3 < 16);
    READ_A(0, 0); READ_B(0, 0, bf0);
    stageA(1, 0, t + 1);
    bar_top(); MFMAQ(0, 0, bf0); bar_end();
    READ_B(0, 1, bf1);
    stageA(1, 1, t + 1);
    bar_top(); MFMAQ(0, 1, bf1); bar_end();
    READ_A(0, 1);
    if (s2) stageB(0, 0, t + 2);
    bar_top(); MFMAQ(1, 0, bf0); bar_end();
    if (s2) stageB(0, 1, t + 2);
    bar_top(); MFMAQ(1, 1, bf1);
    if (s2) { WAIT_VM(4); } else { WAIT_VM(0); }
    bar_end();
    READ_A(1, 0); READ_B(1, 0, bf0);
    if (s2) stageA(0, 0, t + 2);
    bar_top(); MFMAQ(0, 0, bf0); bar_end();
    READ_B(1, 1, bf1);
    if (s2) stageA(0, 1, t + 2);
    bar_top(); MFMAQ(0, 1, bf1); bar_end();
    READ_A(1, 1);
    if (s3) stageB(1, 0, t + 3);
    bar_top(); MFMAQ(1, 0, bf0); bar_end();
    if (s3) stageB(1, 1, t + 3);
    bar_top(); MFMAQ(1, 1, bf1);
    WAIT_VM(4);
    bar_end();
  }
}

// ---------------- GEMM1 (SWAPPED): C[qkv_dim][token] = wqkvT · x^T ----------------
// A = wqkvT (3072 x 1024 K-major), B = xb (32768 x 1024 K-major).
// C/D layout now has row = qkv-dim d per lane-quad (j-axis) -> rope pairs are
// register-adjacent (0 shfl), norm = 16 in-lane squares + shfl_xor(16/32) over g.
// q,k: [w][head][key512][d64] (normed+roped).  v: [w][head][d64][key512].
__global__ __launch_bounds__(512, 2) void k_gemm_qkv(const short* __restrict__ A, const short* __restrict__ Bt,
                                                     const float* __restrict__ bias,
                                                     const float* __restrict__ gq, const float* __restrict__ gk,
                                                     const float2* __restrict__ ctab,
                                                     short* __restrict__ qw, short* __restrict__ kw,
                                                     short* __restrict__ vw) {
  __shared__ __align__(16) short lds[65536];
  const int nwg = gridDim.x, q8 = nwg >> 3, bid = blockIdx.x;
  const int sb = (bid & 7) * q8 + (bid >> 3);          // bijective XCD swizzle
  const int bx = sb % 128, by = sb / 128;              // consecutive sb share A-panel
  const int tileM = by * 256, tileN = bx * 256;        // M = qkv-dims, N = tokens
  f32x4 acc[8][4];
  gemm256_core(A, Bt, tileM, tileN, lds, acc);

  const int tid = threadIdx.x, lane = tid & 63, wid = tid >> 6;
  const int wr = wid >> 2, wc = wid & 3, g = lane >> 4, r = lane & 15;
  const int part = tileM >> 10;                        // block-uniform: 0=q 1=k 2=v
  const int rowabs = tileM + wr * 128;                 // absolute qkv-dim base of wave
  const int rowloc = rowabs & 1023;                    // within-part

  // per-thread token decode (4 tokens: ni axis)
  int tw[4], tidx[4], tcx[4], tcy[4], tcz[4];
#pragma unroll
  for (int ni = 0; ni < 4; ++ni) {
    int tok = tileN + wc * 64 + ni * 16 + r;
    int gx = tok >> 10, gy = (tok >> 5) & 31, gz = tok & 31;
    tw[ni] = ((gx >> 3) << 4) | ((gy >> 3) << 2) | (gz >> 3);
    tidx[ni] = ((gx & 7) << 6) | ((gy & 7) << 3) | (gz & 7);
    tcx[ni] = gx; tcy[ni] = gy; tcz[ni] = gz;
  }

  if (part < 2) {
    __syncthreads();
    float2* ctl = (float2*)lds;
    if (tid < 320) ctl[tid] = ctab[tid];
    __syncthreads();
    short* buf = (part == 0) ? qw : kw;
    const float* gamma = (part == 0) ? gq : gk;
    // q: fold score-scale 1/sqrt(D) AND log2(e) (attn uses exp2); k: sqrt(D)=8.
    const float qk_sc = (part == 0) ? 1.4426950408889634f : 8.0f;
#pragma unroll
    for (int hh = 0; hh < 2; ++hh) {                   // 2 heads per wave
      const int head = (rowloc >> 6) + hh;
      float gam[4][4], bv[4][4];
#pragma unroll
      for (int mh = 0; mh < 4; ++mh)
#pragma unroll
        for (int j = 0; j < 4; ++j) {
          int d = mh * 16 + g * 4 + j;
          gam[mh][j] = gamma[head * 64 + d];
          bv[mh][j] = bias[rowabs + hh * 64 + mh * 16 + g * 4 + j];
        }
#pragma unroll
      for (int ni = 0; ni < 4; ++ni) {
        float vv[4][4];
        float ss = 0.f;
#pragma unroll
        for (int mh = 0; mh < 4; ++mh)
#pragma unroll
          for (int j = 0; j < 4; ++j) {
            vv[mh][j] = acc[hh * 4 + mh][ni][j] + bv[mh][j];
            ss += vv[mh][j] * vv[mh][j];
          }
        ss += __shfl_xor(ss, 16);
        ss += __shfl_xor(ss, 32);
        float sc = qk_sc / fmaxf(sqrtf(ss), 1e-12f);
#pragma unroll
        for (int mh = 0; mh < 4; ++mh)
#pragma unroll
          for (int j = 0; j < 4; ++j) vv[mh][j] *= sc * gam[mh][j];
        // rope: pairs (j0,j1),(j2,j3) register-local
#pragma unroll
        for (int mh = 0; mh < 4; ++mh)
#pragma unroll
          for (int pp = 0; pp < 2; ++pp) {
            int p = mh * 8 + g * 2 + pp;               // pair index = d/2
            if (p < 30) {
              int axis = (p >= 20) ? 2 : (p >= 10 ? 1 : 0);
              int fi = p - axis * 10;
              int cc = (axis == 0) ? tcx[ni] : ((axis == 1) ? tcy[ni] : tcz[ni]);
              float2 cs = ctl[cc * 10 + fi];
              float t0 = vv[mh][2 * pp], t1 = vv[mh][2 * pp + 1];
              vv[mh][2 * pp]     = t0 * cs.x - t1 * cs.y;
              vv[mh][2 * pp + 1] = t0 * cs.y + t1 * cs.x;
            }
          }
        size_t base = ((size_t)(tw[ni] * 16 + head) * 512 + tidx[ni]) * 64;
#pragma unroll
        for (int mh = 0; mh < 4; ++mh) {
          s16x4 o4;
#pragma unroll
          for (int j = 0; j < 4; ++j) o4[j] = f2bf(vv[mh][j]);
          *(s16x4*)(buf + base + mh * 16 + g * 4) = o4;
        }
      }
    }
  } else {
    // v: rows are already d -> direct [w][head][d][key] stores (16B key-runs/instr)
#pragma unroll
    for (int hh = 0; hh < 2; ++hh) {
      const int head = (rowloc >> 6) + hh;
      float bv[4][4];
#pragma unroll
      for (int mh = 0; mh < 4; ++mh)
#pragma unroll
        for (int j = 0; j < 4; ++j)
          bv[mh][j] = bias[rowabs + hh * 64 + mh * 16 + g * 4 + j];
#pragma unroll
      for (int ni = 0; ni < 4; ++ni) {
        size_t wb = (size_t)(tw[ni] * 16 + head) * 32768 + tidx[ni];
#pragma unroll
        for (int mh = 0; mh < 4; ++mh)
#pragma unroll
          for (int j = 0; j < 4; ++j) {
            int d = mh * 16 + g * 4 + j;
            vw[wb + (size_t)d * 512] = f2bf(acc[hh * 4 + mh][ni][j] + bv[mh][j]);
          }
      }
    }
  }
}

// ---------------- GEMM2: out = h@Wout + b (fp32 out) ----------------
__global__ __launch_bounds__(512, 2) void k_gemm_out(const short* __restrict__ A, const short* __restrict__ Bt,
                                                     const float* __restrict__ bias, float* __restrict__ out) {
  __shared__ __align__(16) short lds[65536];
  const int nwg = gridDim.x, q8 = nwg >> 3, bid = blockIdx.x;
  const int sb = (bid & 7) * q8 + (bid >> 3);
  const int bx = sb & 3, by = sb >> 2;
  const int tileM = by * 256, tileN = bx * 256;
  f32x4 acc[8][4];
  gemm256_core(A, Bt, tileM, tileN, lds, acc);

  const int tid = threadIdx.x, lane = tid & 63, wid = tid >> 6;
  const int wr = wid >> 2, wc = wid & 3, g = lane >> 4, r = lane & 15;
#pragma unroll
  for (int mi = 0; mi < 8; ++mi)
#pragma unroll
    for (int j = 0; j < 4; ++j) {
      int gr = tileM + wr * 128 + mi * 16 + g * 4 + j;
#pragma unroll
      for (int ni = 0; ni < 4; ++ni) {
        int gc = tileN + wc * 64 + ni * 16 + r;
        out[(size_t)gr * C_DIM + gc] = acc[mi][ni][j] + bias[gc];
      }
    }
}

// ================ attention v3: swapped-QK, V pre-transposed in global ================
__global__ __launch_bounds__(256, 2) void k_attn(const short* __restrict__ qw, const short* __restrict__ kw,
                                                 const short* __restrict__ vw, short* __restrict__ hb) {
  __shared__ __align__(16) short Ks[2][4096];
  __shared__ __align__(16) short Vt[2][4096];
  __shared__ __align__(16) short Pb[4][1024];
  const int b = blockIdx.x;
  const int qh = b & 1, head = (b >> 1) & 15, w = b >> 5;
  const int tid = threadIdx.x, lane = tid & 63, wid = tid >> 6;
  const int g = lane >> 4, r = lane & 15;
  const short* Qp = qw + ((size_t)(w * 16 + head) * 512 + qh * 256 + wid * 64) * 64;
  const short* Kp = kw + (size_t)(w * 16 + head) * 32768;
  const short* Vp = vw + (size_t)(w * 16 + head) * 32768;   // [d64][key512]

  s16x8 qf[4][2];
#pragma unroll
  for (int qt = 0; qt < 4; ++qt)
#pragma unroll
    for (int kh = 0; kh < 2; ++kh)
      qf[qt][kh] = *(const s16x8*)(Qp + (qt * 16 + r) * 64 + kh * 32 + g * 8);

  f32x4 o[4][4];  // O^T: o[qt][nt][j] = O^T[d = nt*16+g*4+j][q = r]
#pragma unroll
  for (int qt = 0; qt < 4; ++qt)
#pragma unroll
    for (int nt = 0; nt < 4; ++nt) o[qt][nt] = (f32x4)0.f;
  float m[4] = {-1e30f, -1e30f, -1e30f, -1e30f};
  float l[4] = {0.f, 0.f, 0.f, 0.f};

  short* PwW = &Pb[wid][0];

  auto stageK = [&](int bufb, int c) {
#pragma unroll
    for (int i = 0; i < 2; ++i) {
      int ci = i * 256 + tid;
      int row = ci >> 3;
      int sc = (ci & 7) ^ (row & 7);
      gload16(Kp + (size_t)(c * 64 + row) * 64 + sc * 8, &Ks[bufb][(i * 256 + (tid & ~63)) * 8]);
    }
  };
  auto stageV = [&](int bufb, int c) {
#pragma unroll
    for (int i = 0; i < 2; ++i) {
      int ci = i * 256 + tid;
      int row = ci >> 3;
      int sc = (ci & 7) ^ (row & 7);
      gload16(Vp + (size_t)row * 512 + c * 64 + sc * 8, &Vt[bufb][(i * 256 + (tid & ~63)) * 8]);
    }
  };

  stageK(0, 0); stageV(0, 0);

#pragma unroll 1
  for (int c = 0; c < 8; ++c) {
    const int cur = c & 1;
    if (c < 7) { stageK(cur ^ 1, c + 1); stageV(cur ^ 1, c + 1); }
    if (c < 7) { WAIT_VM(4); } else { WAIT_VM(0); }
    __builtin_amdgcn_s_barrier();

    s16x8 kf[4][2];
#pragma unroll
    for (int nt = 0; nt < 4; ++nt)
#pragma unroll
      for (int kh = 0; kh < 2; ++kh)
        kf[nt][kh] = *(const s16x8*)(&Ks[cur][0] + (nt * 16 + r) * 64 + (((kh * 4 + g) ^ (r & 7)) << 3));
    s16x8 vfr[4][2];
#pragma unroll
    for (int nt = 0; nt < 4; ++nt)
#pragma unroll
      for (int kh = 0; kh < 2; ++kh)
        vfr[nt][kh] = *(const s16x8*)(&Vt[cur][0] + (nt * 16 + r) * 64 + (((kh * 4 + g) ^ (r & 7)) << 3));

#pragma unroll
    for (int qt = 0; qt < 4; ++qt) {
      f32x4 s4[4];
#pragma unroll
      for (int nt = 0; nt < 4; ++nt) s4[nt] = (f32x4)0.f;
      __builtin_amdgcn_s_setprio(1);
#pragma unroll
      for (int nt = 0; nt < 4; ++nt)
#pragma unroll
        for (int kh = 0; kh < 2; ++kh) s4[nt] = mfma16(kf[nt][kh], qf[qt][kh], s4[nt]);
      __builtin_amdgcn_s_setprio(0);
      float pm = -1e30f;
#pragma unroll
      for (int nt = 0; nt < 4; ++nt)
#pragma unroll
        for (int j = 0; j < 4; ++j) pm = fmaxf(pm, s4[nt][j]);
      pm = fmaxf(pm, __shfl_xor(pm, 16));
      pm = fmaxf(pm, __shfl_xor(pm, 32));
      float mn = fmaxf(m[qt], pm);
      float al = exp2f(m[qt] - mn);
      m[qt] = mn;
      float ps = 0.f;
#pragma unroll
      for (int nt = 0; nt < 4; ++nt)
#pragma unroll
        for (int j = 0; j < 4; ++j) { float p = exp2f(s4[nt][j] - mn); s4[nt][j] = p; ps += p; }
      ps += __shfl_xor(ps, 16);
      ps += __shfl_xor(ps, 32);
      l[qt] = l[qt] * al + ps;
#pragma unroll
      for (int nt = 0; nt < 4; ++nt) o[qt][nt] *= al;
#pragma unroll
      for (int nt = 0; nt < 4; ++nt) {
        uint32_t u0 = (uint32_t)(uint16_t)f2bf(s4[nt][0]) | ((uint32_t)(uint16_t)f2bf(s4[nt][1]) << 16);
        uint32_t u1 = (uint32_t)(uint16_t)f2bf(s4[nt][2]) | ((uint32_t)(uint16_t)f2bf(s4[nt][3]) << 16);
        int col = nt * 16 + g * 4;
        int slot = (col >> 3) ^ (r & 7);
        uint2 uu; uu.x = u0; uu.y = u1;
        *(uint2*)(PwW + r * 64 + slot * 8 + (g & 1) * 4) = uu;
      }
      s16x8 pf0 = *(const s16x8*)(PwW + r * 64 + ((g ^ (r & 7)) << 3));
      s16x8 pf1 = *(const s16x8*)(PwW + r * 64 + (((4 + g) ^ (r & 7)) << 3));
      __builtin_amdgcn_s_setprio(1);
#pragma unroll
      for (int nt = 0; nt < 4; ++nt) {
        o[qt][nt] = mfma16(vfr[nt][0], pf0, o[qt][nt]);
        o[qt][nt] = mfma16(vfr[nt][1], pf1, o[qt][nt]);
      }
      __builtin_amdgcn_s_setprio(0);
    }
    asm volatile("s_waitcnt lgkmcnt(0)" ::: "memory");
    SB();
    __builtin_amdgcn_s_barrier();
  }

#pragma unroll
  for (int qt = 0; qt < 4; ++qt) {
    float inv = 1.f / l[qt];
#pragma unroll
    for (int nt = 0; nt < 4; ++nt) {
      uint32_t u0 = (uint32_t)(uint16_t)f2bf(o[qt][nt][0] * inv) | ((uint32_t)(uint16_t)f2bf(o[qt][nt][1] * inv) << 16);
      uint32_t u1 = (uint32_t)(uint16_t)f2bf(o[qt][nt][2] * inv) | ((uint32_t)(uint16_t)f2bf(o[qt][nt][3] * inv) << 16);
      int col = nt * 16 + g * 4;
      int slot = (col >> 3) ^ (r & 7);
      uint2 uu; uu.x = u0; uu.y = u1;
      *(uint2*)(PwW + r * 64 + slot * 8 + (g & 1) * 4) = uu;
    }
#pragma unroll
    for (int rr = 0; rr < 2; ++rr) {
      int q2 = lane >> 2;
      int cc = (lane & 3) + rr * 4;
      int slot = cc ^ (q2 & 7);
      s16x8 vv = *(const s16x8*)(PwW + q2 * 64 + slot * 8);
      int idx = qh * 256 + wid * 64 + qt * 16 + q2;
      int cx = ((w >> 4) << 3) + (idx >> 6);
      int cy = (((w >> 2) & 3) << 3) + ((idx >> 3) & 7);
      int cz = ((w & 3) << 3) + (idx & 7);
      size_t n = (size_t)cx * 1024 + cy * 32 + cz;
      *(s16x8*)(hb + n * 1024 + head * 64 + cc * 8) = vv;
    }
  }
}

extern "C" void kernel_launch(void* const* d_in, const int* in_sizes, int n_in,
                              void* d_out, int out_size, void* d_ws, size_t ws_size,
                              hipStream_t stream) {
  const float* x    = (const float*)d_in[0];
  const float* Wqkv = (const float*)d_in[2];
  const float* bqkv = (const float*)d_in[3];
  const float* gq   = (const float*)d_in[4];
  const float* gk   = (const float*)d_in[5];
  const float* Wout = (const float*)d_in[6];
  const float* bout = (const float*)d_in[7];
  float* out = (float*)d_out;

  char* ws = (char*)d_ws;
  size_t o = 0;
  auto take = [&](size_t b) { char* p = ws + o; o += (b + 255) & ~(size_t)255; return p; };
  short* xb    = (short*)take((size_t)N_TOK * C_DIM * 2);  // reused as hb after GEMM1
  short* wqkvT = (short*)take((size_t)C3 * C_DIM * 2);
  short* woutT = (short*)take((size_t)C_DIM * C_DIM * 2);
  float2* ctab = (float2*)take(320 * sizeof(float2));
  short* qw    = (short*)take((size_t)N_TOK * C_DIM * 2);
  short* kw    = (short*)take((size_t)N_TOK * C_DIM * 2);
  short* vw    = (short*)take((size_t)N_TOK * C_DIM * 2);
  short* hb = xb;

  k_cvt_x<<<(N_TOK * C_DIM) / (256 * 8), 256, 0, stream>>>(x, xb, ctab);
  k_transpose_all<<<96 * 32 + 32 * 32, 256, 0, stream>>>(Wqkv, wqkvT, Wout, woutT);
  // SWAPPED: A = wqkvT (M=3072), B = xb (N=32768)
  k_gemm_qkv<<<(C3 / 256) * (N_TOK / 256), 512, 0, stream>>>(wqkvT, xb, bqkv, gq, gk, ctab, qw, kw, vw);
  k_attn<<<2048, 256, 0, stream>>>(qw, kw, vw, hb);
  k_gemm_out<<<(C_DIM / 256) * (N_TOK / 256), 512, 0, stream>>>(hb, woutT, bout, out);
}

// Round 12
// 509.843 us; speedup vs baseline: 1.0118x; 1.0118x over previous
//
#include <hip/hip_runtime.h>
#include <hip/hip_bf16.h>
#include <stdint.h>

#define DEV static __device__ __forceinline__

typedef __attribute__((ext_vector_type(4))) float f32x4;
typedef __attribute__((ext_vector_type(8))) short s16x8;
typedef __attribute__((ext_vector_type(4))) short s16x4;

constexpr int N_TOK = 32768;   // 32^3
constexpr int C_DIM = 1024;
constexpr int C3    = 3072;
constexpr int GK    = 1024;    // K for both GEMMs

DEV float bf2f(short u) { union { float f; uint32_t i; } x; x.i = ((uint32_t)(uint16_t)u) << 16; return x.f; }
DEV short f2bf(float f) { union { float f; uint32_t i; } x; x.f = f; uint32_t r = x.i + 0x7FFFu + ((x.i >> 16) & 1u); return (short)(r >> 16); }

DEV f32x4 mfma16(s16x8 a, s16x8 b, f32x4 c) {
  return __builtin_amdgcn_mfma_f32_16x16x32_bf16(a, b, c, 0, 0, 0);
}

DEV void gload16(const void* g, void* lds) {
  __builtin_amdgcn_global_load_lds((const __attribute__((address_space(1))) void*)g,
                                   (__attribute__((address_space(3))) void*)lds, 16, 0, 0);
}

#define SB() __builtin_amdgcn_sched_barrier(0)
#define WAIT_VM(N) do { asm volatile("s_waitcnt vmcnt(" #N ")" ::: "memory"); SB(); } while (0)
DEV void bar_top() { SB(); __builtin_amdgcn_s_barrier(); asm volatile("s_waitcnt lgkmcnt(0)" ::: "memory"); SB(); }
DEV void bar_end() { SB(); __builtin_amdgcn_s_barrier(); SB(); }

// ---------------- fp32 -> bf16 convert (x) + RoPE table (block 0) ----------------
__global__ void k_cvt_x(const float* __restrict__ in, short* __restrict__ outb,
                        float2* __restrict__ ctab) {
  if (blockIdx.x == 0) {
    for (int t = threadIdx.x; t < 320; t += 256) {
      int c = t / 10, fi = t % 10;
      float freq = powf(10000.0f, -(float)fi / 10.0f);
      float ph = (float)c * freq;
      ctab[t] = make_float2(cosf(ph), sinf(ph));
    }
  }
  size_t i = ((size_t)blockIdx.x * 256 + threadIdx.x) * 8;
  float4 a = *(const float4*)(in + i);
  float4 b = *(const float4*)(in + i + 4);
  s16x8 o;
  o[0] = f2bf(a.x); o[1] = f2bf(a.y); o[2] = f2bf(a.z); o[3] = f2bf(a.w);
  o[4] = f2bf(b.x); o[5] = f2bf(b.y); o[6] = f2bf(b.z); o[7] = f2bf(b.w);
  *(s16x8*)(outb + i) = o;
}

// ---------------- transpose + convert both weights (-> [ncol][K] bf16) ----------------
__global__ void k_transpose_all(const float* __restrict__ wqkv, short* __restrict__ wqkvT,
                                const float* __restrict__ wout, short* __restrict__ woutT) {
  __shared__ float t[32][33];
  int b = blockIdx.x;
  const float* in; short* outb; int rin, cin, bx, by;
  if (b < 96 * 32) {
    in = wqkv; outb = wqkvT; rin = C_DIM; cin = C3; bx = b % 96; by = b / 96;
  } else {
    b -= 96 * 32;
    in = wout; outb = woutT; rin = C_DIM; cin = C_DIM; bx = b % 32; by = b / 32;
  }
  int tx = threadIdx.x & 31, ty = threadIdx.x >> 5;
  int c0 = bx * 32, r0 = by * 32;
#pragma unroll
  for (int k = 0; k < 32; k += 8) t[ty + k][tx] = in[(size_t)(r0 + ty + k) * cin + c0 + tx];
  __syncthreads();
#pragma unroll
  for (int k = 0; k < 32; k += 8) outb[(size_t)(c0 + ty + k) * rin + r0 + tx] = f2bf(t[tx][ty + k]);
}

// ================= 256x256 8-phase GEMM (T2+T3+T4+T5) =================
#define READ_A(b, mh) do { _Pragma("unroll") for (int mi_ = 0; mi_ < 4; ++mi_) \
  _Pragma("unroll") for (int kh_ = 0; kh_ < 2; ++kh_) af[mi_ * 2 + kh_] = LDA(b, (mh) * 4 + mi_, kh_); } while (0)
#define READ_B(b, nh, bfx) do { _Pragma("unroll") for (int ni_ = 0; ni_ < 2; ++ni_) \
  _Pragma("unroll") for (int kh_ = 0; kh_ < 2; ++kh_) (bfx)[ni_ * 2 + kh_] = LDB(b, (nh) * 2 + ni_, kh_); } while (0)
#define MFMAQ(mh, nh, bfx) do { __builtin_amdgcn_s_setprio(1); \
  _Pragma("unroll") for (int mi_ = 0; mi_ < 4; ++mi_) \
  _Pragma("unroll") for (int kh_ = 0; kh_ < 2; ++kh_) \
  _Pragma("unroll") for (int ni_ = 0; ni_ < 2; ++ni_) \
    acc[(mh) * 4 + mi_][(nh) * 2 + ni_] = mfma16(af[mi_ * 2 + kh_], (bfx)[ni_ * 2 + kh_], acc[(mh) * 4 + mi_][(nh) * 2 + ni_]); \
  __builtin_amdgcn_s_setprio(0); } while (0)

DEV void gemm256_core(const short* __restrict__ A, const short* __restrict__ Bt,
                      int tileM, int tileN, short* lds, f32x4 (&acc)[8][4]) {
  const int tid = threadIdx.x;
  const int lane = tid & 63, wid = tid >> 6;
  const int wr = wid >> 2, wc = wid & 3;
  const int g = lane >> 4, r = lane & 15;

#pragma unroll
  for (int mi = 0; mi < 8; ++mi)
#pragma unroll
    for (int ni = 0; ni < 4; ++ni) acc[mi][ni] = (f32x4)0.0f;

  const short* Ag = A + (size_t)tileM * GK;
  const short* Bg = Bt + (size_t)tileN * GK;
  const int ldsA = wr * 8192;
  const int ldsB = 16384 + (wc >> 1) * 8192;
  const int brow = (wc & 1) * 64;

  auto stageA = [&](int b, int h, int kt) {
    const short* gb = Ag + (size_t)(h * 128) * GK + kt * 64;
    short* db = lds + b * 32768 + h * 8192 + (tid & 448) * 8;
#pragma unroll
    for (int i = 0; i < 2; ++i) {
      int s = i * 512 + tid;
      int row = s >> 3;
      int c = (s & 7) ^ (row & 7);
      gload16(gb + (size_t)row * GK + c * 8, db + i * 4096);
    }
  };
  auto stageB = [&](int b, int h, int kt) {
    const short* gb = Bg + (size_t)(h * 128) * GK + kt * 64;
    short* db = lds + b * 32768 + 16384 + h * 8192 + (tid & 448) * 8;
#pragma unroll
    for (int i = 0; i < 2; ++i) {
      int s = i * 512 + tid;
      int row = s >> 3;
      int c = (s & 7) ^ (row & 7);
      gload16(gb + (size_t)row * GK + c * 8, db + i * 4096);
    }
  };
  auto LDA = [&](int b, int mi, int kh) -> s16x8 {
    int row = mi * 16 + r;
    int c = (kh * 4 + g) ^ (r & 7);
    return *(const s16x8*)(lds + b * 32768 + ldsA + row * 64 + c * 8);
  };
  auto LDB = [&](int b, int ni, int kh) -> s16x8 {
    int row = brow + ni * 16 + r;
    int c = (kh * 4 + g) ^ (r & 7);
    return *(const s16x8*)(lds + b * 32768 + ldsB + row * 64 + c * 8);
  };

  s16x8 af[8], bf0[4], bf1[4];

  stageA(0, 0, 0); stageA(0, 1, 0); stageB(0, 0, 0); stageB(0, 1, 0);
  stageB(1, 0, 1); stageB(1, 1, 1);
  WAIT_VM(4);
  __builtin_amdgcn_s_barrier();

#pragma unroll 1
  for (int t = 0; t < 16; t += 2) {
    const bool s2 = (t + 2 < 16), s3 = (t + 3 < 16);
    READ_A(0, 0); READ_B(0, 0, bf0);
    stageA(1, 0, t + 1);
    bar_top(); MFMAQ(0, 0, bf0); bar_end();
    READ_B(0, 1, bf1);
    stageA(1, 1, t + 1);
    bar_top(); MFMAQ(0, 1, bf1); bar_end();
    READ_A(0, 1);
    if (s2) stageB(0, 0, t + 2);
    bar_top(); MFMAQ(1, 0, bf0); bar_end();
    if (s2) stageB(0, 1, t + 2);
    bar_top(); MFMAQ(1, 1, bf1);
    if (s2) { WAIT_VM(4); } else { WAIT_VM(0); }
    bar_end();
    READ_A(1, 0); READ_B(1, 0, bf0);
    if (s2) stageA(0, 0, t + 2);
    bar_top(); MFMAQ(0, 0, bf0); bar_end();
    READ_B(1, 1, bf1);
    if (s2) stageA(0, 1, t + 2);
    bar_top(); MFMAQ(0, 1, bf1); bar_end();
    READ_A(1, 1);
    if (s3) stageB(1, 0, t + 3);
    bar_top(); MFMAQ(1, 0, bf0); bar_end();
    if (s3) stageB(1, 1, t + 3);
    bar_top(); MFMAQ(1, 1, bf1);
    WAIT_VM(4);
    bar_end();
  }
}

// ---------------- GEMM1 (SWAPPED): C[qkv_dim][token] = wqkvT · x^T ----------------
// L2 tile order: fast axis over the SMALL operand (12 weight panels) so the big
// token panel stays L2-resident per XCD (R10 had it inverted -> +92MB FETCH).
__global__ __launch_bounds__(512, 2) void k_gemm_qkv(const short* __restrict__ A, const short* __restrict__ Bt,
                                                     const float* __restrict__ bias,
                                                     const float* __restrict__ gq, const float* __restrict__ gk,
                                                     const float2* __restrict__ ctab,
                                                     short* __restrict__ qw, short* __restrict__ kw,
                                                     short* __restrict__ vw) {
  __shared__ __align__(16) short lds[65536];
  const int nwg = gridDim.x, q8 = nwg >> 3, bid = blockIdx.x;
  const int sb = (bid & 7) * q8 + (bid >> 3);          // bijective XCD swizzle
  const int by = sb % 12, bx = sb / 12;                // by = weight tile (fast)
  const int tileM = by * 256, tileN = bx * 256;        // M = qkv-dims, N = tokens
  f32x4 acc[8][4];
  gemm256_core(A, Bt, tileM, tileN, lds, acc);

  const int tid = threadIdx.x, lane = tid & 63, wid = tid >> 6;
  const int wr = wid >> 2, wc = wid & 3, g = lane >> 4, r = lane & 15;
  const int part = tileM >> 10;                        // block-uniform: 0=q 1=k 2=v
  const int rowabs = tileM + wr * 128;                 // absolute qkv-dim base of wave
  const int rowloc = rowabs & 1023;                    // within-part

  int tw[4], tidx[4], tcx[4], tcy[4], tcz[4];
#pragma unroll
  for (int ni = 0; ni < 4; ++ni) {
    int tok = tileN + wc * 64 + ni * 16 + r;
    int gx = tok >> 10, gy = (tok >> 5) & 31, gz = tok & 31;
    tw[ni] = ((gx >> 3) << 4) | ((gy >> 3) << 2) | (gz >> 3);
    tidx[ni] = ((gx & 7) << 6) | ((gy & 7) << 3) | (gz & 7);
    tcx[ni] = gx; tcy[ni] = gy; tcz[ni] = gz;
  }

  if (part < 2) {
    __syncthreads();
    float2* ctl = (float2*)lds;
    if (tid < 320) ctl[tid] = ctab[tid];
    __syncthreads();
    short* buf = (part == 0) ? qw : kw;
    const float* gamma = (part == 0) ? gq : gk;
    const float qk_sc = (part == 0) ? 1.4426950408889634f : 8.0f;
#pragma unroll
    for (int hh = 0; hh < 2; ++hh) {
      const int head = (rowloc >> 6) + hh;
      float gam[4][4], bv[4][4];
#pragma unroll
      for (int mh = 0; mh < 4; ++mh)
#pragma unroll
        for (int j = 0; j < 4; ++j) {
          int d = mh * 16 + g * 4 + j;
          gam[mh][j] = gamma[head * 64 + d];
          bv[mh][j] = bias[rowabs + hh * 64 + mh * 16 + g * 4 + j];
        }
#pragma unroll
      for (int ni = 0; ni < 4; ++ni) {
        float vv[4][4];
        float ss = 0.f;
#pragma unroll
        for (int mh = 0; mh < 4; ++mh)
#pragma unroll
          for (int j = 0; j < 4; ++j) {
            vv[mh][j] = acc[hh * 4 + mh][ni][j] + bv[mh][j];
            ss += vv[mh][j] * vv[mh][j];
          }
        ss += __shfl_xor(ss, 16);
        ss += __shfl_xor(ss, 32);
        float sc = qk_sc / fmaxf(sqrtf(ss), 1e-12f);
#pragma unroll
        for (int mh = 0; mh < 4; ++mh)
#pragma unroll
          for (int j = 0; j < 4; ++j) vv[mh][j] *= sc * gam[mh][j];
#pragma unroll
        for (int mh = 0; mh < 4; ++mh)
#pragma unroll
          for (int pp = 0; pp < 2; ++pp) {
            int p = mh * 8 + g * 2 + pp;
            if (p < 30) {
              int axis = (p >= 20) ? 2 : (p >= 10 ? 1 : 0);
              int fi = p - axis * 10;
              int cc = (axis == 0) ? tcx[ni] : ((axis == 1) ? tcy[ni] : tcz[ni]);
              float2 cs = ctl[cc * 10 + fi];
              float t0 = vv[mh][2 * pp], t1 = vv[mh][2 * pp + 1];
              vv[mh][2 * pp]     = t0 * cs.x - t1 * cs.y;
              vv[mh][2 * pp + 1] = t0 * cs.y + t1 * cs.x;
            }
          }
        size_t base = ((size_t)(tw[ni] * 16 + head) * 512 + tidx[ni]) * 64;
#pragma unroll
        for (int mh = 0; mh < 4; ++mh) {
          s16x4 o4;
#pragma unroll
          for (int j = 0; j < 4; ++j) o4[j] = f2bf(vv[mh][j]);
          *(s16x4*)(buf + base + mh * 16 + g * 4) = o4;
        }
      }
    }
  } else {
#pragma unroll
    for (int hh = 0; hh < 2; ++hh) {
      const int head = (rowloc >> 6) + hh;
      float bv[4][4];
#pragma unroll
      for (int mh = 0; mh < 4; ++mh)
#pragma unroll
        for (int j = 0; j < 4; ++j)
          bv[mh][j] = bias[rowabs + hh * 64 + mh * 16 + g * 4 + j];
#pragma unroll
      for (int ni = 0; ni < 4; ++ni) {
        size_t wb = (size_t)(tw[ni] * 16 + head) * 32768 + tidx[ni];
#pragma unroll
        for (int mh = 0; mh < 4; ++mh)
#pragma unroll
          for (int j = 0; j < 4; ++j) {
            int d = mh * 16 + g * 4 + j;
            vw[wb + (size_t)d * 512] = f2bf(acc[hh * 4 + mh][ni][j] + bv[mh][j]);
          }
      }
    }
  }
}

// ---------------- GEMM2: out = h@Wout + b (fp32 out) ----------------
__global__ __launch_bounds__(512, 2) void k_gemm_out(const short* __restrict__ A, const short* __restrict__ Bt,
                                                     const float* __restrict__ bias, float* __restrict__ out) {
  __shared__ __align__(16) short lds[65536];
  const int nwg = gridDim.x, q8 = nwg >> 3, bid = blockIdx.x;
  const int sb = (bid & 7) * q8 + (bid >> 3);
  const int bx = sb & 3, by = sb >> 2;
  const int tileM = by * 256, tileN = bx * 256;
  f32x4 acc[8][4];
  gemm256_core(A, Bt, tileM, tileN, lds, acc);

  const int tid = threadIdx.x, lane = tid & 63, wid = tid >> 6;
  const int wr = wid >> 2, wc = wid & 3, g = lane >> 4, r = lane & 15;
#pragma unroll
  for (int mi = 0; mi < 8; ++mi)
#pragma unroll
    for (int j = 0; j < 4; ++j) {
      int gr = tileM + wr * 128 + mi * 16 + g * 4 + j;
#pragma unroll
      for (int ni = 0; ni < 4; ++ni) {
        int gc = tileN + wc * 64 + ni * 16 + r;
        out[(size_t)gr * C_DIM + gc] = acc[mi][ni][j] + bias[gc];
      }
    }
}

// ============ attention v4: full-window blocks (K/V staged ONCE per head) ============
// 1024 blocks (w,head) x 512 threads (8 waves); wave owns 64 q-rows. Per-wave code
// identical to v3; staging now single-issue per lane; vmcnt(2) steady-state.
__global__ __launch_bounds__(512, 2) void k_attn(const short* __restrict__ qw, const short* __restrict__ kw,
                                                 const short* __restrict__ vw, short* __restrict__ hb) {
  __shared__ __align__(16) short Ks[2][4096];
  __shared__ __align__(16) short Vt[2][4096];
  __shared__ __align__(16) short Pb[8][1024];
  const int b = blockIdx.x;
  const int head = b & 15, w = b >> 4;
  const int tid = threadIdx.x, lane = tid & 63, wid = tid >> 6;
  const int g = lane >> 4, r = lane & 15;
  const short* Qp = qw + ((size_t)(w * 16 + head) * 512 + wid * 64) * 64;
  const short* Kp = kw + (size_t)(w * 16 + head) * 32768;
  const short* Vp = vw + (size_t)(w * 16 + head) * 32768;   // [d64][key512]

  s16x8 qf[4][2];
#pragma unroll
  for (int qt = 0; qt < 4; ++qt)
#pragma unroll
    for (int kh = 0; kh < 2; ++kh)
      qf[qt][kh] = *(const s16x8*)(Qp + (qt * 16 + r) * 64 + kh * 32 + g * 8);

  f32x4 o[4][4];  // O^T: o[qt][nt][j] = O^T[d = nt*16+g*4+j][q = r]
#pragma unroll
  for (int qt = 0; qt < 4; ++qt)
#pragma unroll
    for (int nt = 0; nt < 4; ++nt) o[qt][nt] = (f32x4)0.f;
  float m[4] = {-1e30f, -1e30f, -1e30f, -1e30f};
  float l[4] = {0.f, 0.f, 0.f, 0.f};

  short* PwW = &Pb[wid][0];

  // 512 threads cover one 8KB chunk in a single issue per lane
  auto stageK = [&](int bufb, int c) {
    int row = tid >> 3;
    int sc = (tid & 7) ^ (row & 7);
    gload16(Kp + (size_t)(c * 64 + row) * 64 + sc * 8, &Ks[bufb][(tid & ~63) * 8]);
  };
  auto stageV = [&](int bufb, int c) {
    int row = tid >> 3;
    int sc = (tid & 7) ^ (row & 7);
    gload16(Vp + (size_t)row * 512 + c * 64 + sc * 8, &Vt[bufb][(tid & ~63) * 8]);
  };

  stageK(0, 0); stageV(0, 0);

#pragma unroll 1
  for (int c = 0; c < 8; ++c) {
    const int cur = c & 1;
    if (c < 7) { stageK(cur ^ 1, c + 1); stageV(cur ^ 1, c + 1); }
    if (c < 7) { WAIT_VM(2); } else { WAIT_VM(0); }
    __builtin_amdgcn_s_barrier();

    s16x8 kf[4][2];
#pragma unroll
    for (int nt = 0; nt < 4; ++nt)
#pragma unroll
      for (int kh = 0; kh < 2; ++kh)
        kf[nt][kh] = *(const s16x8*)(&Ks[cur][0] + (nt * 16 + r) * 64 + (((kh * 4 + g) ^ (r & 7)) << 3));
    s16x8 vfr[4][2];
#pragma unroll
    for (int nt = 0; nt < 4; ++nt)
#pragma unroll
      for (int kh = 0; kh < 2; ++kh)
        vfr[nt][kh] = *(const s16x8*)(&Vt[cur][0] + (nt * 16 + r) * 64 + (((kh * 4 + g) ^ (r & 7)) << 3));

#pragma unroll
    for (int qt = 0; qt < 4; ++qt) {
      f32x4 s4[4];
#pragma unroll
      for (int nt = 0; nt < 4; ++nt) s4[nt] = (f32x4)0.f;
      __builtin_amdgcn_s_setprio(1);
#pragma unroll
      for (int nt = 0; nt < 4; ++nt)
#pragma unroll
        for (int kh = 0; kh < 2; ++kh) s4[nt] = mfma16(kf[nt][kh], qf[qt][kh], s4[nt]);
      __builtin_amdgcn_s_setprio(0);
      float pm = -1e30f;
#pragma unroll
      for (int nt = 0; nt < 4; ++nt)
#pragma unroll
        for (int j = 0; j < 4; ++j) pm = fmaxf(pm, s4[nt][j]);
      pm = fmaxf(pm, __shfl_xor(pm, 16));
      pm = fmaxf(pm, __shfl_xor(pm, 32));
      float mn = fmaxf(m[qt], pm);
      float al = exp2f(m[qt] - mn);
      m[qt] = mn;
      float ps = 0.f;
#pragma unroll
      for (int nt = 0; nt < 4; ++nt)
#pragma unroll
        for (int j = 0; j < 4; ++j) { float p = exp2f(s4[nt][j] - mn); s4[nt][j] = p; ps += p; }
      ps += __shfl_xor(ps, 16);
      ps += __shfl_xor(ps, 32);
      l[qt] = l[qt] * al + ps;
#pragma unroll
      for (int nt = 0; nt < 4; ++nt) o[qt][nt] *= al;
#pragma unroll
      for (int nt = 0; nt < 4; ++nt) {
        uint32_t u0 = (uint32_t)(uint16_t)f2bf(s4[nt][0]) | ((uint32_t)(uint16_t)f2bf(s4[nt][1]) << 16);
        uint32_t u1 = (uint32_t)(uint16_t)f2bf(s4[nt][2]) | ((uint32_t)(uint16_t)f2bf(s4[nt][3]) << 16);
        int col = nt * 16 + g * 4;
        int slot = (col >> 3) ^ (r & 7);
        uint2 uu; uu.x = u0; uu.y = u1;
        *(uint2*)(PwW + r * 64 + slot * 8 + (g & 1) * 4) = uu;
      }
      s16x8 pf0 = *(const s16x8*)(PwW + r * 64 + ((g ^ (r & 7)) << 3));
      s16x8 pf1 = *(const s16x8*)(PwW + r * 64 + (((4 + g) ^ (r & 7)) << 3));
      __builtin_amdgcn_s_setprio(1);
#pragma unroll
      for (int nt = 0; nt < 4; ++nt) {
        o[qt][nt] = mfma16(vfr[nt][0], pf0, o[qt][nt]);
        o[qt][nt] = mfma16(vfr[nt][1], pf1, o[qt][nt]);
      }
      __builtin_amdgcn_s_setprio(0);
    }
    asm volatile("s_waitcnt lgkmcnt(0)" ::: "memory");
    SB();
    __builtin_amdgcn_s_barrier();
  }

#pragma unroll
  for (int qt = 0; qt < 4; ++qt) {
    float inv = 1.f / l[qt];
#pragma unroll
    for (int nt = 0; nt < 4; ++nt) {
      uint32_t u0 = (uint32_t)(uint16_t)f2bf(o[qt][nt][0] * inv) | ((uint32_t)(uint16_t)f2bf(o[qt][nt][1] * inv) << 16);
      uint32_t u1 = (uint32_t)(uint16_t)f2bf(o[qt][nt][2] * inv) | ((uint32_t)(uint16_t)f2bf(o[qt][nt][3] * inv) << 16);
      int col = nt * 16 + g * 4;
      int slot = (col >> 3) ^ (r & 7);
      uint2 uu; uu.x = u0; uu.y = u1;
      *(uint2*)(PwW + r * 64 + slot * 8 + (g & 1) * 4) = uu;
    }
#pragma unroll
    for (int rr = 0; rr < 2; ++rr) {
      int q2 = lane >> 2;
      int cc = (lane & 3) + rr * 4;
      int slot = cc ^ (q2 & 7);
      s16x8 vv = *(const s16x8*)(PwW + q2 * 64 + slot * 8);
      int idx = wid * 64 + qt * 16 + q2;
      int cx = ((w >> 4) << 3) + (idx >> 6);
      int cy = (((w >> 2) & 3) << 3) + ((idx >> 3) & 7);
      int cz = ((w & 3) << 3) + (idx & 7);
      size_t n = (size_t)cx * 1024 + cy * 32 + cz;
      *(s16x8*)(hb + n * 1024 + head * 64 + cc * 8) = vv;
    }
  }
}

extern "C" void kernel_launch(void* const* d_in, const int* in_sizes, int n_in,
                              void* d_out, int out_size, void* d_ws, size_t ws_size,
                              hipStream_t stream) {
  const float* x    = (const float*)d_in[0];
  const float* Wqkv = (const float*)d_in[2];
  const float* bqkv = (const float*)d_in[3];
  const float* gq   = (const float*)d_in[4];
  const float* gk   = (const float*)d_in[5];
  const float* Wout = (const float*)d_in[6];
  const float* bout = (const float*)d_in[7];
  float* out = (float*)d_out;

  char* ws = (char*)d_ws;
  size_t o = 0;
  auto take = [&](size_t b) { char* p = ws + o; o += (b + 255) & ~(size_t)255; return p; };
  short* xb    = (short*)take((size_t)N_TOK * C_DIM * 2);  // reused as hb after GEMM1
  short* wqkvT = (short*)take((size_t)C3 * C_DIM * 2);
  short* woutT = (short*)take((size_t)C_DIM * C_DIM * 2);
  float2* ctab = (float2*)take(320 * sizeof(float2));
  short* qw    = (short*)take((size_t)N_TOK * C_DIM * 2);
  short* kw    = (short*)take((size_t)N_TOK * C_DIM * 2);
  short* vw    = (short*)take((size_t)N_TOK * C_DIM * 2);
  short* hb = xb;

  k_cvt_x<<<(N_TOK * C_DIM) / (256 * 8), 256, 0, stream>>>(x, xb, ctab);
  k_transpose_all<<<96 * 32 + 32 * 32, 256, 0, stream>>>(Wqkv, wqkvT, Wout, woutT);
  // SWAPPED: A = wqkvT (M=3072), B = xb (N=32768)
  k_gemm_qkv<<<(C3 / 256) * (N_TOK / 256), 512, 0, stream>>>(wqkvT, xb, bqkv, gq, gk, ctab, qw, kw, vw);
  k_attn<<<1024, 512, 0, stream>>>(qw, kw, vw, hb);
  k_gemm_out<<<(C_DIM / 256) * (N_TOK / 256), 512, 0, stream>>>(hb, woutT, bout, out);
}